// Round 4
// baseline (177.268 us; speedup 1.0000x reference)
//
#include <hip/hip_runtime.h>
#include <hip/hip_bf16.h>
#include <stdint.h>

typedef unsigned char  u8;
typedef unsigned short u16;
typedef unsigned int   u32;
typedef __attribute__((ext_vector_type(8))) short bf16x8;
typedef __attribute__((ext_vector_type(2))) float f32x2;
typedef __attribute__((ext_vector_type(4))) float f32x4;
typedef __attribute__((ext_vector_type(4))) int   i32x4;
typedef __attribute__((ext_vector_type(2))) u32   u32x2;
typedef __attribute__((ext_vector_type(4))) u32   u32x4;

#define BKT_SHIFT 9       // 512 nodes per bucket
#define BKT_NODES 512
#define CAP 12288         // col slab capacity per bucket (exp 8163 +- 90)
#define BINBLK 512        // chunk = E/512 = 3125 <= 3200 (LDS keys cap)
#define GEMMBLK 512

__device__ __forceinline__ float bf2f(u16 u) { return __uint_as_float(((u32)u) << 16); }
__device__ __forceinline__ u16 f2bf(float f) {
    u32 u = __float_as_uint(f);
    u += 0x7FFFu + ((u >> 16) & 1u);   // round-nearest-even
    return (u16)(u >> 16);
}
__device__ __forceinline__ int pkbf(float a, float b) {
    return (int)__builtin_amdgcn_perm(__float_as_uint(b), __float_as_uint(a), 0x07060302u);
}
__device__ __forceinline__ u8 f2fp8(float v) {
    int p = __builtin_amdgcn_cvt_pk_fp8_f32(v, v, 0, false);
    return (u8)(p & 0xff);
}

// ---------------- fused front: LDS-sort binning  +  MFMA layer-1 dense -----------
// R17: GEMM-path stores coalesced via per-wave LDS transpose.
//   Old: 32 store instrs/tile of 2B/1B elements scattered over 4 row-segments
//   (~800k store segments across the pass). New: stage acc into per-wave LDS
//   (bank-padded; wave-internal, no barrier) then 3 dwordx4 stores/lane,
//   fully coalesced (1024 B contiguous per instr).

__global__ __launch_bounds__(256) void k_front(const float* __restrict__ X,
                                               const float* __restrict__ Ws,
                                               const float* __restrict__ b1,
                                               const float* __restrict__ Wn,
                                               u16* __restrict__ Zb,
                                               u8* __restrict__ Y,
                                               int n,
                                               const int* __restrict__ src,
                                               const int* __restrict__ dst,
                                               int* __restrict__ offT,   // [BINBLK][nb+1]
                                               u32* __restrict__ binned, // [BINBLK][chunk]
                                               int E, int chunk, int nb) {
    __shared__ __align__(16) char sm[31744];
    int t = threadIdx.x;

    if ((int)blockIdx.x < BINBLK) {
        // ---- bin path: LDS counting sort ----
        u32* keys = (u32*)sm;             // chunk <= 3200 -> 12800 B
        int* h    = (int*)(sm + 12800);   // 196*4
        int* cur  = (int*)(sm + 13600);   // 196*4
        int* ws4  = (int*)(sm + 14400);   // 8*4
        int blk = blockIdx.x;
        int beg = blk * chunk, end = min(beg + chunk, E), m = max(0, end - beg);

        for (int i = t; i < nb; i += 256) h[i] = 0;
        __syncthreads();
        for (int i = beg + t; i < end; i += 256) atomicAdd(&h[dst[i] >> BKT_SHIFT], 1);
        __syncthreads();
        // exclusive scan of h[0..nb) with 4 waves
        int v = (t < nb) ? h[t] : 0;
        int lane = t & 63, w = t >> 6;
        int incl = v;
#pragma unroll
        for (int o = 1; o < 64; o <<= 1) {
            int x = __shfl_up(incl, o, 64);
            if (lane >= o) incl += x;
        }
        if (lane == 63) ws4[w] = incl;
        __syncthreads();
        if (t == 0) {
            int run = 0;
#pragma unroll
            for (int i = 0; i < 4; i++) { ws4[4 + i] = run; run += ws4[i]; }
        }
        __syncthreads();
        int excl = incl - v + ws4[4 + w];
        int* orow = offT + (size_t)blk * (nb + 1);
        if (t < nb) { cur[t] = excl; orow[t] = excl; }
        if (t == nb - 1) orow[nb] = excl + v;   // == m
        __syncthreads();
        // scatter into LDS (hot), packed (src<<9)|dstLocal
        for (int i = beg + t; i < end; i += 256) {
            int d = dst[i], bk = d >> BKT_SHIFT;
            int p = atomicAdd(&cur[bk], 1);
            keys[p] = ((u32)src[i] << BKT_SHIFT) | (u32)(d & (BKT_NODES - 1));
        }
        __syncthreads();
        // coalesced writeout
        u32* outp = binned + (size_t)blk * chunk;
        for (int i = t; i < m; i += 256) outp[i] = keys[i];
        return;
    }

    // ---- gemm path (tile loop; frags/bias persist in registers) ----
    u16* wl = (u16*)sm;   // 64*132 u16 = 16896 B
    for (int i = t; i < 8192; i += 256) {
        int k = i >> 7, c = i & 127;
        float wv = (c < 64) ? Ws[k * 64 + c] : Wn[k * 64 + (c - 64)];
        wl[k * 132 + c] = f2bf(wv);
    }
    __syncthreads();

    int wid = t >> 6, lane = t & 63;
    int lrow = lane & 15, lquad = lane >> 4;

    bf16x8 bfrag[8][2];
#pragma unroll
    for (int ct = 0; ct < 8; ct++)
#pragma unroll
        for (int kf = 0; kf < 2; kf++)
#pragma unroll
            for (int j = 0; j < 8; j++)
                bfrag[ct][kf][j] = (short)wl[(kf * 32 + lquad * 8 + j) * 132 + ct * 16 + lrow];

    float bias[4];
#pragma unroll
    for (int ct = 0; ct < 4; ct++) bias[ct] = b1[ct * 16 + lrow];

    // per-wave staging buffers (after wl's 16896 B):
    //   Zs: u16[16][76]  (2432 B, row stride 38 dw -> stage writes conflict-free)
    //   Ys: u8 [16][80]  (1280 B)
    u16* Zs = (u16*)(sm + 16896 + wid * 3712);
    u8*  Ys = (u8*)(sm + 16896 + wid * 3712 + 2432);
    int srow = lane >> 2, sseg = lane & 3;

    int tiles = n >> 4;
    int tstride = GEMMBLK * 4;
    for (int tile = (blockIdx.x - BINBLK) * 4 + wid; tile < tiles; tile += tstride) {
        int nb4 = tile << 4;

        const float* xp = X + (size_t)(nb4 + lrow) * 64 + lquad * 8;
        f32x4 x0 = *(const f32x4*)(xp);
        f32x4 x1 = *(const f32x4*)(xp + 4);
        f32x4 x2 = *(const f32x4*)(xp + 32);
        f32x4 x3 = *(const f32x4*)(xp + 36);
        i32x4 p0, p1;
        p0.x = pkbf(x0.x, x0.y); p0.y = pkbf(x0.z, x0.w);
        p0.z = pkbf(x1.x, x1.y); p0.w = pkbf(x1.z, x1.w);
        p1.x = pkbf(x2.x, x2.y); p1.y = pkbf(x2.z, x2.w);
        p1.z = pkbf(x3.x, x3.y); p1.w = pkbf(x3.z, x3.w);
        bf16x8 af0 = __builtin_bit_cast(bf16x8, p0);
        bf16x8 af1 = __builtin_bit_cast(bf16x8, p1);

        f32x4 acc[8];
#pragma unroll
        for (int ct = 0; ct < 8; ct++) {
            f32x4 c = {0.f, 0.f, 0.f, 0.f};
            c = __builtin_amdgcn_mfma_f32_16x16x32_bf16(af0, bfrag[ct][0], c, 0, 0, 0);
            c = __builtin_amdgcn_mfma_f32_16x16x32_bf16(af1, bfrag[ct][1], c, 0, 0, 0);
            acc[ct] = c;
        }

        // stage: Zs[row][ch] = bf16(acc+bias), Ys[row][ch] = fp8(acc)
        // (wave-internal LDS round-trip; lockstep + lgkmcnt ordering, no barrier)
#pragma unroll
        for (int ct = 0; ct < 4; ct++)
#pragma unroll
            for (int r = 0; r < 4; r++)
                Zs[(lquad * 4 + r) * 76 + ct * 16 + lrow] = f2bf(acc[ct][r] + bias[ct]);
#pragma unroll
        for (int ct = 0; ct < 4; ct++)
#pragma unroll
            for (int r = 0; r < 4; r++)
                Ys[(lquad * 4 + r) * 80 + ct * 16 + lrow] = f2fp8(acc[ct + 4][r]);

        // coalesced writeout: lane covers 32 B of one Zb row + 16 B of one Y row
        u32x4 z0 = *(const u32x4*)&Zs[srow * 76 + sseg * 16];
        u32x4 z1 = *(const u32x4*)&Zs[srow * 76 + sseg * 16 + 8];
        u32x4 yv = *(const u32x4*)&Ys[srow * 80 + sseg * 16];
        *(u32x4*)(Zb + (size_t)(nb4 + srow) * 64 + sseg * 16) = z0;
        *(u32x4*)(Zb + (size_t)(nb4 + srow) * 64 + sseg * 16 + 8) = z1;
        *(u32x4*)(Y + (size_t)(nb4 + srow) * 64 + sseg * 16) = yv;
    }
}

// ------- build 2/2: per-bucket CSR fully in LDS; col written coalesced -----------

__global__ __launch_bounds__(512) void k_csr(const u32* __restrict__ binned,
                                             const int* __restrict__ offT,
                                             int* __restrict__ rpb,
                                             int* __restrict__ rpe,
                                             int* __restrict__ col,
                                             int chunk, int nb, int n) {
    __shared__ __align__(16) u32 ed[CAP];
    __shared__ u32 srt[CAP];
    __shared__ int gst[BINBLK], gln[BINBLK], soff[BINBLK];
    __shared__ int cnt[BKT_NODES];
    __shared__ int wsum[8], woff[8];
    __shared__ int stot;
    int b = blockIdx.x, t = threadIdx.x;
    int lane = t & 63, w = t >> 6;

    {
        const int* row = offT + (size_t)t * (nb + 1);
        int s = row[b], e = row[b + 1];
        gst[t] = t * chunk + s;
        gln[t] = e - s;
    }
    __syncthreads();
    // exclusive scan of gln[0..512) with 8 waves
    int v = gln[t];
    int incl = v;
#pragma unroll
    for (int o = 1; o < 64; o <<= 1) {
        int x = __shfl_up(incl, o, 64);
        if (lane >= o) incl += x;
    }
    if (lane == 63) wsum[w] = incl;
    __syncthreads();
    if (t == 0) {
        int run = 0;
#pragma unroll
        for (int i = 0; i < 8; i++) { woff[i] = run; run += wsum[i]; }
        stot = run;
    }
    __syncthreads();
    soff[t] = incl - v + woff[w];
    __syncthreads();
    int total = min(stot, CAP);
    // gather segments into LDS
    for (int k = w; k < BINBLK; k += 8) {
        int g = gst[k], L = gln[k], o = soff[k];
        for (int i = lane; i < L && o + i < CAP; i += 64) ed[o + i] = binned[g + i];
    }
    cnt[t] = 0;
    __syncthreads();
    for (int i = t; i < total; i += 512)
        atomicAdd(&cnt[ed[i] & (BKT_NODES - 1)], 1);
    __syncthreads();
    int v2 = cnt[t];
    int incl2 = v2;
#pragma unroll
    for (int o = 1; o < 64; o <<= 1) {
        int x = __shfl_up(incl2, o, 64);
        if (lane >= o) incl2 += x;
    }
    if (lane == 63) wsum[w] = incl2;
    __syncthreads();
    if (t == 0) {
        int run = 0;
#pragma unroll
        for (int i = 0; i < 8; i++) { woff[i] = run; run += wsum[i]; }
    }
    __syncthreads();
    int excl2 = incl2 - v2 + woff[w];
    int gnode = b * BKT_NODES + t;
    int cb = b * CAP;
    if (gnode < n) { rpb[gnode] = cb + excl2; rpe[gnode] = cb + excl2 + v2; }
    cnt[t] = excl2;   // reuse as cursor
    __syncthreads();
    for (int i = t; i < total; i += 512) {
        u32 e = ed[i];
        int p = atomicAdd(&cnt[e & (BKT_NODES - 1)], 1);
        srt[p] = e >> BKT_SHIFT;
    }
    __syncthreads();
    for (int i = t; i < total; i += 512) col[cb + i] = (int)srt[i];
}

// ------- Layer 1 aggregate + Layer 2 dense fused -------
// R17: unroll to 8 edges/iter — issue 2 col i32x4 + 8 independent Y loads
//   before consuming any (MLP 4->8 per group, 64 per wave). Latency-bound
//   regime: throughput ~ outstanding misses.

__global__ __launch_bounds__(256) void k_gather1f(const int* __restrict__ rpb,
                                                  const int* __restrict__ rpe,
                                                  const int* __restrict__ col,
                                                  const u16* __restrict__ Zb,
                                                  const u8* __restrict__ Y,
                                                  const float* __restrict__ Ws2,
                                                  const float* __restrict__ b2,
                                                  const float* __restrict__ Wn2,
                                                  float* __restrict__ P,
                                                  u16* __restrict__ Q, int n) {
    __shared__ float wl[64 * 9];   // permuted [row'][8 cols + pad]
    int t = threadIdx.x;
    // stage W: row' = (k&7)*8 + (k>>3), cols 0-3 = Ws2, 4-7 = Wn2
    for (int i = t; i < 512; i += 256) {
        int k = i >> 3, c = i & 7;
        float v = (c < 4) ? Ws2[k * 4 + c] : Wn2[k * 4 + (c - 4)];
        wl[((k & 7) * 8 + (k >> 3)) * 9 + c] = v;
    }
    float bb0 = b2[0], bb1 = b2[1], bb2 = b2[2], bb3 = b2[3];
    __syncthreads();

    int w = t >> 6;                 // wave 0-3
    int g = (t >> 3) & 7;           // group within wave, 8 lanes each
    int l8 = t & 7;                 // lane within group: owns channels [l8*8, l8*8+8)
    int node = blockIdx.x * 32 + w * 8 + g;
    if (node >= n) return;

    int beg = rpb[node], end = rpe[node];
    float a[8];
#pragma unroll
    for (int j = 0; j < 8; j++) a[j] = 0.f;

    const u8* yb = Y + (size_t)l8 * 8;
    int e = beg;
    for (; e + 8 <= end; e += 8) {
        i32x4 c0 = *(const i32x4*)(col + e);
        i32x4 c1 = *(const i32x4*)(col + e + 4);
        u32x2 y0 = *(const u32x2*)(yb + (size_t)c0.x * 64);
        u32x2 y1 = *(const u32x2*)(yb + (size_t)c0.y * 64);
        u32x2 y2 = *(const u32x2*)(yb + (size_t)c0.z * 64);
        u32x2 y3 = *(const u32x2*)(yb + (size_t)c0.w * 64);
        u32x2 y4 = *(const u32x2*)(yb + (size_t)c1.x * 64);
        u32x2 y5 = *(const u32x2*)(yb + (size_t)c1.y * 64);
        u32x2 y6 = *(const u32x2*)(yb + (size_t)c1.z * 64);
        u32x2 y7 = *(const u32x2*)(yb + (size_t)c1.w * 64);
#pragma unroll
        for (int j = 0; j < 8; j++) {
            u32x2 yw = (j == 0) ? y0 : (j == 1) ? y1 : (j == 2) ? y2 : (j == 3) ? y3
                     : (j == 4) ? y4 : (j == 5) ? y5 : (j == 6) ? y6 : y7;
            f32x2 lo0 = __builtin_amdgcn_cvt_pk_f32_fp8(yw.x, false);
            f32x2 hi0 = __builtin_amdgcn_cvt_pk_f32_fp8(yw.x, true);
            f32x2 lo1 = __builtin_amdgcn_cvt_pk_f32_fp8(yw.y, false);
            f32x2 hi1 = __builtin_amdgcn_cvt_pk_f32_fp8(yw.y, true);
            a[0] += lo0.x; a[1] += lo0.y; a[2] += hi0.x; a[3] += hi0.y;
            a[4] += lo1.x; a[5] += lo1.y; a[6] += hi1.x; a[7] += hi1.y;
        }
    }
    for (; e + 4 <= end; e += 4) {
        i32x4 cv = *(const i32x4*)(col + e);
        u32x2 y0 = *(const u32x2*)(yb + (size_t)cv.x * 64);
        u32x2 y1 = *(const u32x2*)(yb + (size_t)cv.y * 64);
        u32x2 y2 = *(const u32x2*)(yb + (size_t)cv.z * 64);
        u32x2 y3 = *(const u32x2*)(yb + (size_t)cv.w * 64);
#pragma unroll
        for (int j = 0; j < 4; j++) {
            u32x2 yw = (j == 0) ? y0 : (j == 1) ? y1 : (j == 2) ? y2 : y3;
            f32x2 lo0 = __builtin_amdgcn_cvt_pk_f32_fp8(yw.x, false);
            f32x2 hi0 = __builtin_amdgcn_cvt_pk_f32_fp8(yw.x, true);
            f32x2 lo1 = __builtin_amdgcn_cvt_pk_f32_fp8(yw.y, false);
            f32x2 hi1 = __builtin_amdgcn_cvt_pk_f32_fp8(yw.y, true);
            a[0] += lo0.x; a[1] += lo0.y; a[2] += hi0.x; a[3] += hi0.y;
            a[4] += lo1.x; a[5] += lo1.y; a[6] += hi1.x; a[7] += hi1.y;
        }
    }
    for (; e < end; e++) {
        u32x2 yw = *(const u32x2*)(yb + (size_t)col[e] * 64);
        f32x2 lo0 = __builtin_amdgcn_cvt_pk_f32_fp8(yw.x, false);
        f32x2 hi0 = __builtin_amdgcn_cvt_pk_f32_fp8(yw.x, true);
        f32x2 lo1 = __builtin_amdgcn_cvt_pk_f32_fp8(yw.y, false);
        f32x2 hi1 = __builtin_amdgcn_cvt_pk_f32_fp8(yw.y, true);
        a[0] += lo0.x; a[1] += lo0.y; a[2] += hi0.x; a[3] += hi0.y;
        a[4] += lo1.x; a[5] += lo1.y; a[6] += hi1.x; a[7] += hi1.y;
    }

    float deg = (float)(end - beg);
    float inv = (deg > 0.f) ? 1.f / deg : 0.f;
    // self term: lane's 8 channels of Zb row (16 B aligned)
    u32x4 zr = *(const u32x4*)(Zb + (size_t)node * 64 + l8 * 8);
    float h[8];
#pragma unroll
    for (int j = 0; j < 8; j++) {
        u32 word = (j < 2) ? zr.x : (j < 4) ? zr.y : (j < 6) ? zr.z : zr.w;
        u16 zv = (j & 1) ? (u16)(word >> 16) : (u16)(word & 0xffff);
        h[j] = tanhf(bf2f(zv) + a[j] * inv);
    }

    // layer-2: r[c] = sum_k h[k]*W[k][c]; lane's rows at wl[(j*8+l8)*9 + c]
    float r[8];
#pragma unroll
    for (int c = 0; c < 8; c++) r[c] = 0.f;
#pragma unroll
    for (int j = 0; j < 8; j++) {
        float hj = h[j];
        const float* wp = &wl[(j * 8 + l8) * 9];
#pragma unroll
        for (int c = 0; c < 8; c++) r[c] += hj * wp[c];
    }
#pragma unroll
    for (int m = 1; m < 8; m <<= 1)
#pragma unroll
        for (int c = 0; c < 8; c++) r[c] += __shfl_xor(r[c], m, 64);

    if (l8 == 0) {
        *(float4*)(P + (size_t)node * 4) =
            make_float4(r[0] + bb0, r[1] + bb1, r[2] + bb2, r[3] + bb3);
        ushort4 qv;
        qv.x = f2bf(r[4]); qv.y = f2bf(r[5]); qv.z = f2bf(r[6]); qv.w = f2bf(r[7]);
        *(ushort4*)(Q + (size_t)node * 4) = qv;
    }
}

// ---------------- Layer 2 aggregate: out = P + mean(Q[neigh])  (f32 out) ---------
// R17: 16 lanes/node — at deg~16 every lane issues exactly 1 col + 1 Q load,
//   all 64 per wave independent (was 2 dependent col->Q rounds per lane).

__global__ __launch_bounds__(256) void k_gather2(const int* __restrict__ rpb,
                                                 const int* __restrict__ rpe,
                                                 const int* __restrict__ col,
                                                 const float* __restrict__ P,
                                                 const u16* __restrict__ Q,
                                                 float* __restrict__ out, int n) {
    int t = threadIdx.x;
    int g = t >> 4, l = t & 15;             // 16 lanes/node, 16 nodes/block
    int node = blockIdx.x * 16 + g;
    if (node >= n) return;
    int beg = rpb[node], end = rpe[node];
    float a0 = 0.f, a1 = 0.f, a2 = 0.f, a3 = 0.f;
    for (int e = beg + l; e < end; e += 16) {
        ushort4 qv = *(const ushort4*)(Q + (size_t)col[e] * 4);
        a0 += bf2f(qv.x); a1 += bf2f(qv.y); a2 += bf2f(qv.z); a3 += bf2f(qv.w);
    }
#pragma unroll
    for (int m = 1; m < 16; m <<= 1) {
        a0 += __shfl_xor(a0, m, 64);
        a1 += __shfl_xor(a1, m, 64);
        a2 += __shfl_xor(a2, m, 64);
        a3 += __shfl_xor(a3, m, 64);
    }
    if (l == 0) {
        float deg = (float)(end - beg);
        float inv = (deg > 0.f) ? 1.f / deg : 0.f;
        float4 p = *(const float4*)(P + (size_t)node * 4);
        *(float4*)(out + (size_t)node * 4) =
            make_float4(p.x + a0 * inv, p.y + a1 * inv,
                        p.z + a2 * inv, p.w + a3 * inv);
    }
}

// ---------------- launch ----------------

extern "C" void kernel_launch(void* const* d_in, const int* in_sizes, int n_in,
                              void* d_out, int out_size, void* d_ws, size_t ws_size,
                              hipStream_t stream) {
    const float* X   = (const float*)d_in[0];
    const int* esrc  = (const int*)d_in[1];
    const int* edst  = (const int*)d_in[2];
    const float* Ws1 = (const float*)d_in[3];
    const float* b1  = (const float*)d_in[4];
    const float* Wn1 = (const float*)d_in[5];
    const float* Ws2 = (const float*)d_in[6];
    const float* b2  = (const float*)d_in[7];
    const float* Wn2 = (const float*)d_in[8];
    float* out = (float*)d_out;

    const int n = in_sizes[0] / 64;   // 100000
    const int E = in_sizes[1];        // 1600000
    const int nb = (n + BKT_NODES - 1) >> BKT_SHIFT;  // 196
    const int chunk = (E + BINBLK - 1) / BINBLK;      // 3125 (must be <= 3200)

    size_t off = 0;
    char* base = (char*)d_ws;
    auto give = [&](size_t bytes) -> char* {
        char* p = base + off;
        off += (bytes + 255) & ~(size_t)255;
        return p;
    };
    int*   offT   = (int*)give((size_t)BINBLK * (nb + 1) * 4);
    int*   rpb    = (int*)give((size_t)n * 4);
    int*   rpe    = (int*)give((size_t)n * 4);
    u32*   binned = (u32*)give((size_t)BINBLK * chunk * 4);
    int*   col    = (int*)give((size_t)nb * CAP * 4);
    u16*   Zb     = (u16*)give((size_t)n * 64 * 2);
    u8*    Y      = (u8*)give((size_t)n * 64);
    float* P      = (float*)give((size_t)n * 4 * 4);
    u16*   Q      = (u16*)give((size_t)n * 4 * 2);

    // 1) fused: LDS-sort binning (coalesced writes) + layer-1 dense (MFMA)
    k_front<<<BINBLK + GEMMBLK, 256, 0, stream>>>(
        X, Ws1, b1, Wn1, Zb, Y, n,
        esrc, edst, offT, binned, E, chunk, nb);

    // 2) per-bucket CSR, fully in LDS, coalesced col write
    k_csr<<<nb, 512, 0, stream>>>(binned, offT, rpb, rpe, col, chunk, nb, n);

    // 3) gather1 + layer-2 dense fused (fp8 Y, 8 lanes/node, 8-edge unroll)
    k_gather1f<<<(n + 31) / 32, 256, 0, stream>>>(rpb, rpe, col, Zb, Y,
                                                  Ws2, b2, Wn2, P, Q, n);
    // 4) layer-2 aggregate: 16 lanes/node, 16 nodes/block
    k_gather2<<<(n + 15) / 16, 256, 0, stream>>>(rpb, rpe, col, P, Q, out, n);
}

// Round 5
// 157.066 us; speedup vs baseline: 1.1286x; 1.1286x over previous
//
#include <hip/hip_runtime.h>
#include <hip/hip_bf16.h>
#include <stdint.h>

typedef unsigned char  u8;
typedef unsigned short u16;
typedef unsigned int   u32;
typedef __attribute__((ext_vector_type(8))) short bf16x8;
typedef __attribute__((ext_vector_type(2))) float f32x2;
typedef __attribute__((ext_vector_type(4))) float f32x4;
typedef __attribute__((ext_vector_type(4))) int   i32x4;
typedef __attribute__((ext_vector_type(2))) u32   u32x2;
typedef __attribute__((ext_vector_type(4))) u32   u32x4;

// R18: buckets 512 -> 256 nodes; csr + gather1 fused into one kernel (edge
// list stays in LDS for the layer-1 gather; col written only for gather2).
#define BKT_SHIFT 8       // 256 nodes per bucket
#define BKT_NODES 256
#define CAP 5120          // per-bucket slab (mean 4092, sd ~64 -> +16 sigma)
#define BINBLK 512        // chunk = E/512 = 3125 <= 3200 (LDS keys cap)
#define GEMMBLK 512

__device__ __forceinline__ float bf2f(u16 u) { return __uint_as_float(((u32)u) << 16); }
__device__ __forceinline__ u16 f2bf(float f) {
    u32 u = __float_as_uint(f);
    u += 0x7FFFu + ((u >> 16) & 1u);   // round-nearest-even
    return (u16)(u >> 16);
}
__device__ __forceinline__ int pkbf(float a, float b) {
    return (int)__builtin_amdgcn_perm(__float_as_uint(b), __float_as_uint(a), 0x07060302u);
}
__device__ __forceinline__ u8 f2fp8(float v) {
    int p = __builtin_amdgcn_cvt_pk_fp8_f32(v, v, 0, false);
    return (u8)(p & 0xff);
}

// ---------------- fused front: LDS-sort binning  +  MFMA layer-1 dense -----------

__global__ __launch_bounds__(256) void k_front(const float* __restrict__ X,
                                               const float* __restrict__ Ws,
                                               const float* __restrict__ b1,
                                               const float* __restrict__ Wn,
                                               u16* __restrict__ Zb,
                                               u8* __restrict__ Y,
                                               int n,
                                               const int* __restrict__ src,
                                               const int* __restrict__ dst,
                                               int* __restrict__ offT,   // [BINBLK][nb+1]
                                               u32* __restrict__ binned, // [BINBLK][chunk]
                                               int E, int chunk, int nb) {
    __shared__ __align__(16) char sm[31744];
    int t = threadIdx.x;

    if ((int)blockIdx.x < BINBLK) {
        // ---- bin path: LDS counting sort (nb = 391 buckets) ----
        u32* keys = (u32*)sm;             // chunk <= 3200 -> 12800 B
        int* h    = (int*)(sm + 12800);   // 391*4 -> 1600 B slot
        int* cur  = (int*)(sm + 14400);   // 1600 B slot
        int* ws4  = (int*)(sm + 16000);   // 8*4
        int blk = blockIdx.x;
        int beg = blk * chunk, end = min(beg + chunk, E), m = max(0, end - beg);

        for (int i = t; i < nb; i += 256) h[i] = 0;
        __syncthreads();
        for (int i = beg + t; i < end; i += 256) atomicAdd(&h[dst[i] >> BKT_SHIFT], 1);
        __syncthreads();
        // exclusive scan of h[0..nb), 2 consecutive elements per thread (nb<=512)
        int lane = t & 63, w = t >> 6;
        int e0 = 2 * t, e1 = 2 * t + 1;
        int h0 = (e0 < nb) ? h[e0] : 0;
        int h1 = (e1 < nb) ? h[e1] : 0;
        int s = h0 + h1;
        int incl = s;
#pragma unroll
        for (int o = 1; o < 64; o <<= 1) {
            int x = __shfl_up(incl, o, 64);
            if (lane >= o) incl += x;
        }
        if (lane == 63) ws4[w] = incl;
        __syncthreads();
        if (t == 0) {
            int run = 0;
#pragma unroll
            for (int i = 0; i < 4; i++) { ws4[4 + i] = run; run += ws4[i]; }
        }
        __syncthreads();
        int excl = incl - s + ws4[4 + w];
        int* orow = offT + (size_t)blk * (nb + 1);
        if (e0 < nb) { cur[e0] = excl;      orow[e0] = excl; }
        if (e1 < nb) { cur[e1] = excl + h0; orow[e1] = excl + h0; }
        if (t == 255) orow[nb] = excl + s;   // == m
        __syncthreads();
        // scatter into LDS (hot), packed (src<<8)|dstLocal
        for (int i = beg + t; i < end; i += 256) {
            int d = dst[i], bk = d >> BKT_SHIFT;
            int p = atomicAdd(&cur[bk], 1);
            keys[p] = ((u32)src[i] << BKT_SHIFT) | (u32)(d & (BKT_NODES - 1));
        }
        __syncthreads();
        // coalesced writeout
        u32* outp = binned + (size_t)blk * chunk;
        for (int i = t; i < m; i += 256) outp[i] = keys[i];
        return;
    }

    // ---- gemm path (tile loop; frags/bias persist in registers) ----
    u16* wl = (u16*)sm;   // 64*132 u16 = 16896 B
    for (int i = t; i < 8192; i += 256) {
        int k = i >> 7, c = i & 127;
        float wv = (c < 64) ? Ws[k * 64 + c] : Wn[k * 64 + (c - 64)];
        wl[k * 132 + c] = f2bf(wv);
    }
    __syncthreads();

    int wid = t >> 6, lane = t & 63;
    int lrow = lane & 15, lquad = lane >> 4;

    bf16x8 bfrag[8][2];
#pragma unroll
    for (int ct = 0; ct < 8; ct++)
#pragma unroll
        for (int kf = 0; kf < 2; kf++)
#pragma unroll
            for (int j = 0; j < 8; j++)
                bfrag[ct][kf][j] = (short)wl[(kf * 32 + lquad * 8 + j) * 132 + ct * 16 + lrow];

    float bias[4];
#pragma unroll
    for (int ct = 0; ct < 4; ct++) bias[ct] = b1[ct * 16 + lrow];

    // per-wave staging buffers (after wl's 16896 B):
    u16* Zs = (u16*)(sm + 16896 + wid * 3712);
    u8*  Ys = (u8*)(sm + 16896 + wid * 3712 + 2432);
    int srow = lane >> 2, sseg = lane & 3;

    int tiles = n >> 4;
    int tstride = GEMMBLK * 4;
    for (int tile = (blockIdx.x - BINBLK) * 4 + wid; tile < tiles; tile += tstride) {
        int nb4 = tile << 4;

        const float* xp = X + (size_t)(nb4 + lrow) * 64 + lquad * 8;
        f32x4 x0 = *(const f32x4*)(xp);
        f32x4 x1 = *(const f32x4*)(xp + 4);
        f32x4 x2 = *(const f32x4*)(xp + 32);
        f32x4 x3 = *(const f32x4*)(xp + 36);
        i32x4 p0, p1;
        p0.x = pkbf(x0.x, x0.y); p0.y = pkbf(x0.z, x0.w);
        p0.z = pkbf(x1.x, x1.y); p0.w = pkbf(x1.z, x1.w);
        p1.x = pkbf(x2.x, x2.y); p1.y = pkbf(x2.z, x2.w);
        p1.z = pkbf(x3.x, x3.y); p1.w = pkbf(x3.z, x3.w);
        bf16x8 af0 = __builtin_bit_cast(bf16x8, p0);
        bf16x8 af1 = __builtin_bit_cast(bf16x8, p1);

        f32x4 acc[8];
#pragma unroll
        for (int ct = 0; ct < 8; ct++) {
            f32x4 c = {0.f, 0.f, 0.f, 0.f};
            c = __builtin_amdgcn_mfma_f32_16x16x32_bf16(af0, bfrag[ct][0], c, 0, 0, 0);
            c = __builtin_amdgcn_mfma_f32_16x16x32_bf16(af1, bfrag[ct][1], c, 0, 0, 0);
            acc[ct] = c;
        }

#pragma unroll
        for (int ct = 0; ct < 4; ct++)
#pragma unroll
            for (int r = 0; r < 4; r++)
                Zs[(lquad * 4 + r) * 76 + ct * 16 + lrow] = f2bf(acc[ct][r] + bias[ct]);
#pragma unroll
        for (int ct = 0; ct < 4; ct++)
#pragma unroll
            for (int r = 0; r < 4; r++)
                Ys[(lquad * 4 + r) * 80 + ct * 16 + lrow] = f2fp8(acc[ct + 4][r]);

        u32x4 z0 = *(const u32x4*)&Zs[srow * 76 + sseg * 16];
        u32x4 z1 = *(const u32x4*)&Zs[srow * 76 + sseg * 16 + 8];
        u32x4 yv = *(const u32x4*)&Ys[srow * 80 + sseg * 16];
        *(u32x4*)(Zb + (size_t)(nb4 + srow) * 64 + sseg * 16) = z0;
        *(u32x4*)(Zb + (size_t)(nb4 + srow) * 64 + sseg * 16 + 8) = z1;
        *(u32x4*)(Y + (size_t)(nb4 + srow) * 64 + sseg * 16) = yv;
    }
}

// ------- FUSED: per-bucket CSR sort in LDS + layer-1 gather + layer-2 dense ------
// The sorted edge list (srt) never leaves LDS for the gather; col/rpb/rpe are
// written only for k_gather2. One bucket (256 nodes, ~4092 edges) per block.

__global__ __launch_bounds__(512) void k_csrg1(const u32* __restrict__ binned,
                                               const int* __restrict__ offT,
                                               const u16* __restrict__ Zb,
                                               const u8* __restrict__ Y,
                                               const float* __restrict__ Ws2,
                                               const float* __restrict__ b2,
                                               const float* __restrict__ Wn2,
                                               int* __restrict__ rpb,
                                               int* __restrict__ rpe,
                                               int* __restrict__ col,
                                               float* __restrict__ P,
                                               u16* __restrict__ Q,
                                               int chunk, int nb, int n) {
    __shared__ __align__(16) u32 ed[CAP];
    __shared__ __align__(16) u32 srt[CAP];
    __shared__ int gst[BINBLK], gln[BINBLK], soff[BINBLK];
    __shared__ int cnt[BKT_NODES];
    __shared__ float wl[64 * 9];     // layer-2 weights, permuted
    __shared__ int wsum[8], woff[8];
    __shared__ int stot;
    int b = blockIdx.x, t = threadIdx.x;
    int lane = t & 63, w = t >> 6;

    // phase A: stage layer-2 weights + per-chunk segment bounds
    {
        int k = t >> 3, c = t & 7;   // t<512 -> one entry each
        float v = (c < 4) ? Ws2[k * 4 + c] : Wn2[k * 4 + (c - 4)];
        wl[((k & 7) * 8 + (k >> 3)) * 9 + c] = v;
    }
    {
        const int* row = offT + (size_t)t * (nb + 1);
        int s = row[b], e = row[b + 1];
        gst[t] = t * chunk + s;
        gln[t] = e - s;
    }
    float bb0 = b2[0], bb1 = b2[1], bb2 = b2[2], bb3 = b2[3];
    __syncthreads();

    // phase B: exclusive scan of gln[0..512)
    int v = gln[t];
    int incl = v;
#pragma unroll
    for (int o = 1; o < 64; o <<= 1) {
        int x = __shfl_up(incl, o, 64);
        if (lane >= o) incl += x;
    }
    if (lane == 63) wsum[w] = incl;
    __syncthreads();
    if (t == 0) {
        int run = 0;
#pragma unroll
        for (int i = 0; i < 8; i++) { woff[i] = run; run += wsum[i]; }
        stot = run;
    }
    __syncthreads();
    soff[t] = incl - v + woff[w];
    __syncthreads();
    int total = min(stot, CAP);

    // phase C: fill ed from binned; 8-lane sub-groups, 64 segments in flight
    {
        int sg = lane >> 3, sl = lane & 7;
        for (int k0 = w * 8 + sg; k0 < BINBLK; k0 += 64) {
            int g = gst[k0], L = gln[k0], o = soff[k0];
            for (int i = sl; i < L; i += 8)
                if (o + i < CAP) ed[o + i] = binned[g + i];
        }
    }
    if (t < BKT_NODES) cnt[t] = 0;
    __syncthreads();

    // phase D: histogram by dstLocal
    for (int i = t; i < total; i += 512)
        atomicAdd(&cnt[ed[i] & (BKT_NODES - 1)], 1);
    __syncthreads();

    // phase E: scan cnt[0..256) (first 4 waves carry data), write rpb/rpe
    int v2 = (t < BKT_NODES) ? cnt[t] : 0;
    int incl2 = v2;
#pragma unroll
    for (int o = 1; o < 64; o <<= 1) {
        int x = __shfl_up(incl2, o, 64);
        if (lane >= o) incl2 += x;
    }
    if (lane == 63) wsum[w] = incl2;
    __syncthreads();
    if (t == 0) {
        int run = 0;
#pragma unroll
        for (int i = 0; i < 8; i++) { woff[i] = run; run += wsum[i]; }
    }
    __syncthreads();
    int excl2 = incl2 - v2 + woff[w];
    int cb = b * CAP;
    if (t < BKT_NODES) {
        int gnode = b * BKT_NODES + t;
        if (gnode < n) { rpb[gnode] = cb + excl2; rpe[gnode] = cb + excl2 + v2; }
        gst[t] = excl2;   // reuse: per-node row start (LDS)
        gln[t] = v2;      // reuse: per-node degree   (LDS)
        cnt[t] = excl2;   // cursor for scatter
    }
    __syncthreads();

    // phase F: scatter into sorted order
    for (int i = t; i < total; i += 512) {
        u32 e = ed[i];
        int p = atomicAdd(&cnt[e & (BKT_NODES - 1)], 1);
        srt[p] = e >> BKT_SHIFT;
    }
    __syncthreads();

    // phase G: write col for k_gather2 (coalesced)
    for (int i = t; i < total; i += 512) col[cb + i] = (int)srt[i];

    // phase H: layer-1 gather (Y rows, fp8) + layer-2 dense, edges from LDS
    int gid = t >> 3, l8 = t & 7;   // 8 lanes per node
    const u8* yb = Y + (size_t)l8 * 8;
#pragma unroll 1
    for (int r = 0; r < 4; r++) {
        int ln_ = gid + r * 64;                  // local node 0..255
        int node = b * BKT_NODES + ln_;
        if (node >= n) continue;                 // uniform per 8-lane group
        int s0 = gst[ln_], L = gln[ln_];
        float a[8];
#pragma unroll
        for (int j = 0; j < 8; j++) a[j] = 0.f;
        int e = 0;
        for (; e + 8 <= L; e += 8) {
            int s_[8];
#pragma unroll
            for (int j = 0; j < 8; j++) s_[j] = (int)srt[s0 + e + j];
            u32x2 y_[8];
#pragma unroll
            for (int j = 0; j < 8; j++) y_[j] = *(const u32x2*)(yb + (size_t)s_[j] * 64);
#pragma unroll
            for (int j = 0; j < 8; j++) {
                f32x2 lo0 = __builtin_amdgcn_cvt_pk_f32_fp8(y_[j].x, false);
                f32x2 hi0 = __builtin_amdgcn_cvt_pk_f32_fp8(y_[j].x, true);
                f32x2 lo1 = __builtin_amdgcn_cvt_pk_f32_fp8(y_[j].y, false);
                f32x2 hi1 = __builtin_amdgcn_cvt_pk_f32_fp8(y_[j].y, true);
                a[0] += lo0.x; a[1] += lo0.y; a[2] += hi0.x; a[3] += hi0.y;
                a[4] += lo1.x; a[5] += lo1.y; a[6] += hi1.x; a[7] += hi1.y;
            }
        }
        for (; e < L; e++) {
            int sj = (int)srt[s0 + e];
            u32x2 yw = *(const u32x2*)(yb + (size_t)sj * 64);
            f32x2 lo0 = __builtin_amdgcn_cvt_pk_f32_fp8(yw.x, false);
            f32x2 hi0 = __builtin_amdgcn_cvt_pk_f32_fp8(yw.x, true);
            f32x2 lo1 = __builtin_amdgcn_cvt_pk_f32_fp8(yw.y, false);
            f32x2 hi1 = __builtin_amdgcn_cvt_pk_f32_fp8(yw.y, true);
            a[0] += lo0.x; a[1] += lo0.y; a[2] += hi0.x; a[3] += hi0.y;
            a[4] += lo1.x; a[5] += lo1.y; a[6] += hi1.x; a[7] += hi1.y;
        }

        float deg = (float)L;
        float inv = (deg > 0.f) ? 1.f / deg : 0.f;
        u32x4 zr = *(const u32x4*)(Zb + (size_t)node * 64 + l8 * 8);
        float h[8];
#pragma unroll
        for (int j = 0; j < 8; j++) {
            u32 word = (j < 2) ? zr.x : (j < 4) ? zr.y : (j < 6) ? zr.z : zr.w;
            u16 zv = (j & 1) ? (u16)(word >> 16) : (u16)(word & 0xffff);
            h[j] = tanhf(bf2f(zv) + a[j] * inv);
        }

        float rr[8];
#pragma unroll
        for (int c = 0; c < 8; c++) rr[c] = 0.f;
#pragma unroll
        for (int j = 0; j < 8; j++) {
            float hj = h[j];
            const float* wp = &wl[(j * 8 + l8) * 9];
#pragma unroll
            for (int c = 0; c < 8; c++) rr[c] += hj * wp[c];
        }
#pragma unroll
        for (int m = 1; m < 8; m <<= 1)
#pragma unroll
            for (int c = 0; c < 8; c++) rr[c] += __shfl_xor(rr[c], m, 64);

        if (l8 == 0) {
            *(float4*)(P + (size_t)node * 4) =
                make_float4(rr[0] + bb0, rr[1] + bb1, rr[2] + bb2, rr[3] + bb3);
            ushort4 qv;
            qv.x = f2bf(rr[4]); qv.y = f2bf(rr[5]); qv.z = f2bf(rr[6]); qv.w = f2bf(rr[7]);
            *(ushort4*)(Q + (size_t)node * 4) = qv;
        }
    }
}

// ---------------- Layer 2 aggregate: out = P + mean(Q[neigh])  (f32 out) ---------

__global__ __launch_bounds__(256) void k_gather2(const int* __restrict__ rpb,
                                                 const int* __restrict__ rpe,
                                                 const int* __restrict__ col,
                                                 const float* __restrict__ P,
                                                 const u16* __restrict__ Q,
                                                 float* __restrict__ out, int n) {
    int t = threadIdx.x;
    int g = t >> 4, l = t & 15;             // 16 lanes/node, 16 nodes/block
    int node = blockIdx.x * 16 + g;
    if (node >= n) return;
    int beg = rpb[node], end = rpe[node];
    float a0 = 0.f, a1 = 0.f, a2 = 0.f, a3 = 0.f;
    for (int e = beg + l; e < end; e += 16) {
        ushort4 qv = *(const ushort4*)(Q + (size_t)col[e] * 4);
        a0 += bf2f(qv.x); a1 += bf2f(qv.y); a2 += bf2f(qv.z); a3 += bf2f(qv.w);
    }
#pragma unroll
    for (int m = 1; m < 16; m <<= 1) {
        a0 += __shfl_xor(a0, m, 64);
        a1 += __shfl_xor(a1, m, 64);
        a2 += __shfl_xor(a2, m, 64);
        a3 += __shfl_xor(a3, m, 64);
    }
    if (l == 0) {
        float deg = (float)(end - beg);
        float inv = (deg > 0.f) ? 1.f / deg : 0.f;
        float4 p = *(const float4*)(P + (size_t)node * 4);
        *(float4*)(out + (size_t)node * 4) =
            make_float4(p.x + a0 * inv, p.y + a1 * inv,
                        p.z + a2 * inv, p.w + a3 * inv);
    }
}

// ---------------- launch ----------------

extern "C" void kernel_launch(void* const* d_in, const int* in_sizes, int n_in,
                              void* d_out, int out_size, void* d_ws, size_t ws_size,
                              hipStream_t stream) {
    const float* X   = (const float*)d_in[0];
    const int* esrc  = (const int*)d_in[1];
    const int* edst  = (const int*)d_in[2];
    const float* Ws1 = (const float*)d_in[3];
    const float* b1  = (const float*)d_in[4];
    const float* Wn1 = (const float*)d_in[5];
    const float* Ws2 = (const float*)d_in[6];
    const float* b2  = (const float*)d_in[7];
    const float* Wn2 = (const float*)d_in[8];
    float* out = (float*)d_out;

    const int n = in_sizes[0] / 64;   // 100000
    const int E = in_sizes[1];        // 1600000
    const int nb = (n + BKT_NODES - 1) >> BKT_SHIFT;  // 391
    const int chunk = (E + BINBLK - 1) / BINBLK;      // 3125 (must be <= 3200)

    size_t off = 0;
    char* base = (char*)d_ws;
    auto give = [&](size_t bytes) -> char* {
        char* p = base + off;
        off += (bytes + 255) & ~(size_t)255;
        return p;
    };
    int*   offT   = (int*)give((size_t)BINBLK * (nb + 1) * 4);
    int*   rpb    = (int*)give((size_t)n * 4);
    int*   rpe    = (int*)give((size_t)n * 4);
    u32*   binned = (u32*)give((size_t)BINBLK * chunk * 4);
    int*   col    = (int*)give((size_t)nb * CAP * 4);
    u16*   Zb     = (u16*)give((size_t)n * 64 * 2);
    u8*    Y      = (u8*)give((size_t)n * 64);
    float* P      = (float*)give((size_t)n * 4 * 4);
    u16*   Q      = (u16*)give((size_t)n * 4 * 2);

    // 1) fused: LDS-sort binning (coalesced writes) + layer-1 dense (MFMA)
    k_front<<<BINBLK + GEMMBLK, 256, 0, stream>>>(
        X, Ws1, b1, Wn1, Zb, Y, n,
        esrc, edst, offT, binned, E, chunk, nb);

    // 2) fused: per-bucket CSR sort + layer-1 aggregate + layer-2 dense
    k_csrg1<<<nb, 512, 0, stream>>>(binned, offT, Zb, Y, Ws2, b2, Wn2,
                                    rpb, rpe, col, P, Q, chunk, nb, n);

    // 3) layer-2 aggregate: 16 lanes/node, 16 nodes/block
    k_gather2<<<(n + 15) / 16, 256, 0, stream>>>(rpb, rpe, col, P, Q, out, n);
}